// Round 2
// baseline (1569.939 us; speedup 1.0000x reference)
//
#include <hip/hip_runtime.h>
#include <math.h>

// Problem constants: B=256, T=512, D=128, H=128 (3H=384), U=64, A=10, LAMDA=0.5
#define B_ 256
#define T_ 512
#define D_ 128
#define H_ 128
#define BH_ 32768      // B_*H_
#define NG 1308160     // 511*256*10 gumbels per agent

// LDS-ordering-only barrier: skips the vmcnt(0) drain __syncthreads() forces.
__device__ __forceinline__ void bar_lds() {
  asm volatile("s_waitcnt lgkmcnt(0)\n\ts_barrier" ::: "memory");
}

// quad reductions on the VALU pipe (DPP), not the LDS pipe
__device__ __forceinline__ float dpp_add_xor1(float v) {
  int r = __builtin_amdgcn_update_dpp(0, __float_as_int(v), 0xB1, 0xF, 0xF, true);
  return v + __int_as_float(r);
}
__device__ __forceinline__ float dpp_add_xor2(float v) {
  int r = __builtin_amdgcn_update_dpp(0, __float_as_int(v), 0x4E, 0xF, 0xF, true);
  return v + __int_as_float(r);
}

// fast transcendentals (v_exp/v_rcp based, no div, no branches; ~3 ulp)
__device__ __forceinline__ float frcp(float x) { return __builtin_amdgcn_rcpf(x); }
__device__ __forceinline__ float fsigmoid(float x) { return frcp(1.0f + __expf(-x)); }
__device__ __forceinline__ float ftanh_(float x) { return 1.0f - 2.0f * frcp(1.0f + __expf(2.0f * x)); }

// ---------------- threefry2x32 (exact JAX semantics) ----------------
__device__ __forceinline__ void tf2x32(unsigned k0, unsigned k1, unsigned x0, unsigned x1,
                                       unsigned& o0, unsigned& o1) {
  unsigned k2 = k0 ^ k1 ^ 0x1BD11BDAu;
  unsigned v0 = x0 + k0, v1 = x1 + k1;
#define TFR(r) { v0 += v1; v1 = (v1 << (r)) | (v1 >> (32 - (r))); v1 ^= v0; }
  TFR(13) TFR(15) TFR(26) TFR(6)   v0 += k1; v1 += k2 + 1u;
  TFR(17) TFR(29) TFR(16) TFR(24)  v0 += k2; v1 += k0 + 2u;
  TFR(13) TFR(15) TFR(26) TFR(6)   v0 += k0; v1 += k1 + 3u;
  TFR(17) TFR(29) TFR(16) TFR(24)  v0 += k1; v1 += k2 + 4u;
  TFR(13) TFR(15) TFR(26) TFR(6)   v0 += k2; v1 += k0 + 5u;
#undef TFR
  o0 = v0; o1 = v1;
}

__device__ __forceinline__ float gumbel_f(unsigned bits) {
  const float tiny = 1.17549435e-38f;
  float u = __uint_as_float((bits >> 9) | 0x3f800000u) - 1.0f;
  u = u + tiny;
  u = fmaxf(tiny, u);
  return -__logf(-__logf(u));
}

// ---------------- P0: split keys (jax_threefry_partitionable=True) ----------------
__global__ void p0_keys(unsigned* __restrict__ keys_tab) {
  int i = blockIdx.x * blockDim.x + threadIdx.x;
  if (i >= 1024) return;
  unsigned o0, o1;
  tf2x32(0u, 42u, 0u, (unsigned)i, o0, o1);
  keys_tab[2 * i] = o0; keys_tab[2 * i + 1] = o1;
}

// ---------------- G: tiled fp32 GEMM, N=448 (384 gi cols + 64 a2-hidden cols) ----------
// Block tile 256m x 64n, 256 threads, micro 16m x 4n, K staged in 4 chunks of 32.
// nb==6 reads a2w1/a2b1, applies fast tanh, writes z table [M][64].
#define SX 264
#define SW 72
__global__ __launch_bounds__(256, 4) void gemm_tiled(
    const float* __restrict__ x, const float* __restrict__ w_ih,
    const float* __restrict__ b_ih, const float* __restrict__ a2w1,
    const float* __restrict__ a2b1, float* __restrict__ gi, float* __restrict__ zt) {
  __shared__ __align__(16) float Xs[32 * SX];
  __shared__ __align__(16) float Ws[32 * SW];
  const int tid = threadIdx.x;
  const int mb = blockIdx.x & 511;          // 512 m-tiles
  const int nb = blockIdx.x >> 9;           // 0..6
  const bool isz = (nb == 6);
  const size_t m0 = (size_t)mb * 256;
  const int n0 = isz ? 0 : nb * 64;
  const float* wsrc = isz ? a2w1 : w_ih;
  const float* bsrc = isz ? a2b1 : b_ih;
  const int mt = tid >> 4;                  // 0..15 -> rows mt*16..+15
  const int nt = tid & 15;                  // 0..15 -> cols nt*4..+3
  const int kg = tid >> 5;                  // staging: k-group 0..7
  const int ri = tid & 31;                  // staging: row-in-pass

  float acc[16][4];
  #pragma unroll
  for (int i = 0; i < 16; i++)
    #pragma unroll
    for (int j = 0; j < 4; j++) acc[i][j] = 0.f;

  #pragma unroll 1
  for (int kc = 0; kc < 4; kc++) {
    const int k0 = kc * 32;
    __syncthreads();
    #pragma unroll
    for (int p = 0; p < 8; p++) {
      int row = ri + 32 * p;
      float4 v = *(const float4*)(x + (m0 + row) * 128 + k0 + 4 * kg);
      Xs[(4 * kg + 0) * SX + row] = v.x;
      Xs[(4 * kg + 1) * SX + row] = v.y;
      Xs[(4 * kg + 2) * SX + row] = v.z;
      Xs[(4 * kg + 3) * SX + row] = v.w;
    }
    #pragma unroll
    for (int p = 0; p < 2; p++) {
      int n = ri + 32 * p;
      float4 v = *(const float4*)(wsrc + (size_t)(n0 + n) * 128 + k0 + 4 * kg);
      Ws[(4 * kg + 0) * SW + n] = v.x;
      Ws[(4 * kg + 1) * SW + n] = v.y;
      Ws[(4 * kg + 2) * SW + n] = v.z;
      Ws[(4 * kg + 3) * SW + n] = v.w;
    }
    __syncthreads();
    #pragma unroll 4
    for (int kk = 0; kk < 32; kk++) {
      const float* xrow = Xs + kk * SX + mt * 16;
      float4 xa0 = ((const float4*)xrow)[0];
      float4 xa1 = ((const float4*)xrow)[1];
      float4 xa2 = ((const float4*)xrow)[2];
      float4 xa3 = ((const float4*)xrow)[3];
      float4 wv = *(const float4*)(Ws + kk * SW + nt * 4);
      float xv[16] = {xa0.x, xa0.y, xa0.z, xa0.w, xa1.x, xa1.y, xa1.z, xa1.w,
                      xa2.x, xa2.y, xa2.z, xa2.w, xa3.x, xa3.y, xa3.z, xa3.w};
      #pragma unroll
      for (int i = 0; i < 16; i++) {
        acc[i][0] += xv[i] * wv.x;
        acc[i][1] += xv[i] * wv.y;
        acc[i][2] += xv[i] * wv.z;
        acc[i][3] += xv[i] * wv.w;
      }
    }
  }
  float4 bias = *(const float4*)(bsrc + n0 + nt * 4);
  if (!isz) {
    #pragma unroll
    for (int i = 0; i < 16; i++) {
      float4 o;
      o.x = acc[i][0] + bias.x; o.y = acc[i][1] + bias.y;
      o.z = acc[i][2] + bias.z; o.w = acc[i][3] + bias.w;
      size_t m = m0 + (size_t)mt * 16 + i;
      *(float4*)(gi + m * 384 + n0 + nt * 4) = o;
    }
  } else {
    #pragma unroll
    for (int i = 0; i < 16; i++) {
      float4 o;
      o.x = ftanh_(acc[i][0] + bias.x); o.y = ftanh_(acc[i][1] + bias.y);
      o.z = ftanh_(acc[i][2] + bias.z); o.w = ftanh_(acc[i][3] + bias.w);
      size_t m = m0 + (size_t)mt * 16 + i;
      *(float4*)(zt + m * 64 + nt * 4) = o;
    }
  }
}

// ---------------- SAMP: a2 logits+gumbel+argmax AND g1 gumbel table ----------------
// block = one t (511 blocks); wave per sample, z prefetch pipelined.
// w2s padded to [10][68]: row stride 64 put all 10 'a' rows on the same banks
// (a*64 % 32 == 0) -> 10-way conflict on the dot; stride 68 -> 2-way (free).
__global__ __launch_bounds__(256) void sampler(
    const float* __restrict__ zt, const float* __restrict__ w2,
    const float* __restrict__ b2, const unsigned* __restrict__ keys_tab,
    float* __restrict__ g1, int* __restrict__ a2_tab) {
  __shared__ __align__(16) float w2s[10][68];
  __shared__ float b2s[10];
  __shared__ __align__(16) float zs[4][64];
  const int tid = threadIdx.x, w = tid >> 6, lane = tid & 63;
  const int t = blockIdx.x + 1;
  for (int i = tid; i < 640; i += 256) w2s[i >> 6][i & 63] = w2[i];
  if (tid < 10) b2s[tid] = b2[tid];
  __syncthreads();
  const unsigned k0a = keys_tab[2 * (2 * t + 1)], k1a = keys_tab[2 * (2 * t + 1) + 1];
  const unsigned k0g = keys_tab[2 * (2 * t)],     k1g = keys_tab[2 * (2 * t) + 1];
  const int a = lane & 15, kc = lane >> 4;
  float zr = zt[((size_t)w * 512 + t) * 64 + lane];   // b = w (it=0)
  #pragma unroll 1
  for (int it = 0; it < 64; it++) {
    const int b = 4 * it + w;
    zs[w][lane] = zr;
    if (it < 63) zr = zt[((size_t)(b + 4) * 512 + t) * 64 + lane];
    float p = 0.f;
    if (a < 10) {
      const float4* zp = (const float4*)(&zs[w][16 * kc]);
      const float4* wp = (const float4*)(&w2s[a][16 * kc]);
      #pragma unroll
      for (int c = 0; c < 4; c++) {
        float4 zv = zp[c], w4 = wp[c];
        p += w4.x * zv.x + w4.y * zv.y + w4.z * zv.z + w4.w * zv.w;
      }
    }
    p += __shfl_xor(p, 16);
    p += __shfl_xor(p, 32);
    float val = -3.0e38f;
    if (a < 10 && kc == 0) {
      unsigned o0, o1;
      tf2x32(k0a, k1a, 0u, (unsigned)(b * 10 + a), o0, o1);
      val = (p + b2s[a]) + gumbel_f(o0 ^ o1);
      tf2x32(k0g, k1g, 0u, (unsigned)(b * 10 + a), o0, o1);
      g1[((size_t)(t - 1) * 256 + b) * 10 + a] = gumbel_f(o0 ^ o1);
    }
    float best = 0.f; int bi = 0;
    #pragma unroll
    for (int aa = 0; aa < 10; aa++) {
      float v = __shfl(val, aa);
      if (aa == 0 || v > best) { best = v; bi = aa; }
    }
    if (lane == 0) a2_tab[(size_t)(t - 1) * 256 + b] = bi;
  }
}

// ---------------- S: sequential per-batch kernel (1 block = 1 batch elem) ----------------
// Restructured vs previous best:
//  - gate phase on waves 0-3 x 32 lanes (all 4 SIMDs active instead of 2)
//  - yc transposed to [slot][j][4]={r,z,n,-} -> 3x ds_read_b128 instead of 9x b32
//  - ghi transposed to [j][4]={gi_r+bhh_r, gi_z+bhh_z, gi_n, bhh_n} -> 1x b128
//  - obs 9-element ring sum computed by waves 6/7 in phase 1 (identical fp order)
//  - 2-step-deep global prefetch (gi/g1/a2) via unroll-by-2 with named reg sets
//  - %10 via carried tmod register; hprev in register; lastbuf -> direct store
//  - w2buf padded [10][68] (same 10-way bank conflict as sampler)
__global__ __launch_bounds__(512, 2) void seq_kernel(
    const float* __restrict__ gi_glob, const int* __restrict__ mask,
    const float* __restrict__ w_hh, const float* __restrict__ b_hh,
    const float* __restrict__ a1w1, const float* __restrict__ a1b1,
    const float* __restrict__ a1w2, const float* __restrict__ a1b2,
    const float* __restrict__ g1_tab, const int* __restrict__ a2_tab,
    float* __restrict__ out) {
  __shared__ __align__(16) float ring2[20][128];  // doubled ring: h_s at [s%10] and [s%10+10]
  __shared__ __align__(16) float yct[10][512];    // [slot][j*4+gate], gate: 0=r 1=z 2=n
  __shared__ __align__(16) float ghi4[512];       // [j*4+{r,z,n,bhh_n}], staged per step
  __shared__ __align__(16) float hbuf[128];       // h_{t-1}
  __shared__ __align__(16) float obs[128];        // mean of ring
  __shared__ __align__(16) float osum[128];       // sum of 9 oldest ring entries (phase 1)
  __shared__ __align__(16) float z1buf[64];
  __shared__ __align__(16) float w2buf[10][68];   // padded (bank conflicts)
  __shared__ float b1s[64], b2s[10];
  __shared__ float g1buf[10];
  __shared__ __align__(16) float2 pl2[16];
  __shared__ int a2s_lds;
  __shared__ int redi[8];
  __shared__ int last_s;

  const int tid = threadIdx.x;
  const int wv = tid >> 6, lane = tid & 63;
  const int b = blockIdx.x;
  const int q = tid >> 2, qk = tid & 3;

  // ---- register-resident W_hh for waves 0-5: rows 4q+i, k-quad qk ----
  float4 wr[4][8];
  if (tid < 384) {
    #pragma unroll
    for (int i = 0; i < 4; i++) {
      const float* basep = w_hh + (size_t)(4 * q + i) * 128 + 4 * qk;
      #pragma unroll
      for (int c = 0; c < 8; c++) wr[i][c] = *(const float4*)(basep + 16 * c);
    }
  }
  // ---- register-resident a1w1 for waves 6/7 ----
  float4 w1reg[16];
  if (wv >= 6) {
    int m = ((wv - 6) << 5) + (lane >> 1);
    int kc = lane & 1;
    const float4* wp = (const float4*)(a1w1 + (size_t)m * 128 + 64 * kc);
    #pragma unroll
    for (int c = 0; c < 16; c++) w1reg[c] = wp[c];
  }
  // ---- wave 6: bhh regs + 2-deep gi prefetch (sets A=odd t, B=even t) ----
  float bhh6[6] = {0.f, 0.f, 0.f, 0.f, 0.f, 0.f};
  float gA[6] = {0.f, 0.f, 0.f, 0.f, 0.f, 0.f};
  float gB[6] = {0.f, 0.f, 0.f, 0.f, 0.f, 0.f};
  float g1A = 0.f, g1B = 0.f;
  int a2A = 0, a2B = 0;
  if (wv == 6) {
    bhh6[0] = b_hh[lane];       bhh6[1] = b_hh[128 + lane]; bhh6[2] = b_hh[256 + lane];
    bhh6[3] = b_hh[64 + lane];  bhh6[4] = b_hh[192 + lane]; bhh6[5] = b_hh[320 + lane];
    size_t p1 = ((size_t)b * 512 + 1) * 384;
    gA[0] = gi_glob[p1 + lane];      gA[1] = gi_glob[p1 + 128 + lane]; gA[2] = gi_glob[p1 + 256 + lane];
    gA[3] = gi_glob[p1 + 64 + lane]; gA[4] = gi_glob[p1 + 192 + lane]; gA[5] = gi_glob[p1 + 320 + lane];
    size_t p2 = ((size_t)b * 512 + 2) * 384;
    gB[0] = gi_glob[p2 + lane];      gB[1] = gi_glob[p2 + 128 + lane]; gB[2] = gi_glob[p2 + 256 + lane];
    gB[3] = gi_glob[p2 + 64 + lane]; gB[4] = gi_glob[p2 + 192 + lane]; gB[5] = gi_glob[p2 + 320 + lane];
  }
  if (wv == 7) {
    if (lane < 10) {
      g1A = g1_tab[(size_t)b * 10 + lane];                  // idx (t-1)=0, for t=1
      g1B = g1_tab[((size_t)1 * 256 + b) * 10 + lane];      // idx 1, for t=2
    }
    if (lane == 12) { a2A = a2_tab[b]; a2B = a2_tab[256 + b]; }
  }

  // ---- LDS init ----
  for (int idx = tid; idx < 2560; idx += 512) ((float*)ring2)[idx] = 0.f;
  for (int idx = tid; idx < 5120; idx += 512) ((float*)yct)[idx] = 0.f;
  for (int idx = tid; idx < 640; idx += 512) w2buf[idx >> 6][idx & 63] = a1w2[idx];
  if (tid < 64) b1s[tid] = a1b1[tid];
  if (tid < 10) b2s[tid] = a1b2[tid];
  int mv = mask[(size_t)b * T_ + tid];
  #pragma unroll
  for (int off = 1; off < 64; off <<= 1) mv += __shfl_xor(mv, off);
  if (lane == 0) redi[wv] = mv;
  __syncthreads();
  if (tid == 0) {
    int s = 0;
    #pragma unroll
    for (int w = 0; w < 8; w++) s += redi[w];
    last_s = s - 1;
  }
  __syncthreads();
  const int last = last_s;

  // ---- t = 0: h0 = gru(x0, 0); obs for t=1 (gate threads: waves 0-3, lanes 0-31) ----
  float hprev = 0.f;
  if (wv < 4 && lane < 32) {
    const int j = (wv << 5) + lane;
    const float* g0 = gi_glob + (size_t)b * 512 * 384;
    float r  = fsigmoid(g0[j] + b_hh[j]);
    float zz = fsigmoid(g0[128 + j] + b_hh[128 + j]);
    float n  = ftanh_(g0[256 + j] + r * b_hh[256 + j]);
    float hnew = (1.0f - zz) * n;
    hbuf[j] = hnew; ring2[0][j] = hnew; ring2[10][j] = hnew;
    obs[j] = hnew / 10.0f;
    out[BH_ + ((size_t)b * 512) * 128 + j] = hnew;
    if (0 == last) out[(size_t)b * H_ + j] = hnew;
    hprev = hnew;
  }
  bar_lds();

  int tmod = 1;  // t % 10, carried

  auto step = [&](int t, float (&gr)[6], float& g1r, int& a2r) {
    const int sn = (tmod == 0) ? 9 : tmod - 1;   // slot of h_{t-1}
    // -------- phase 1 --------
    if (tid < 384) {
      // yc[sn] = W_hh * h_{t-1}; thread tid owns row tid (4q+qk == tid)
      const float4* hb4 = (const float4*)hbuf;
      float4 a0 = make_float4(0.f, 0.f, 0.f, 0.f), a1v = a0, a2v = a0, a3v = a0;
      #pragma unroll
      for (int c = 0; c < 8; c++) {
        float4 h4 = hb4[4 * c + qk];
        a0.x += wr[0][c].x * h4.x; a0.y += wr[0][c].y * h4.y; a0.z += wr[0][c].z * h4.z; a0.w += wr[0][c].w * h4.w;
        a1v.x += wr[1][c].x * h4.x; a1v.y += wr[1][c].y * h4.y; a1v.z += wr[1][c].z * h4.z; a1v.w += wr[1][c].w * h4.w;
        a2v.x += wr[2][c].x * h4.x; a2v.y += wr[2][c].y * h4.y; a2v.z += wr[2][c].z * h4.z; a2v.w += wr[2][c].w * h4.w;
        a3v.x += wr[3][c].x * h4.x; a3v.y += wr[3][c].y * h4.y; a3v.z += wr[3][c].z * h4.z; a3v.w += wr[3][c].w * h4.w;
      }
      float s0  = (a0.x + a0.y) + (a0.z + a0.w);
      float s1v = (a1v.x + a1v.y) + (a1v.z + a1v.w);
      float s2v = (a2v.x + a2v.y) + (a2v.z + a2v.w);
      float s3v = (a3v.x + a3v.y) + (a3v.z + a3v.w);
      s0  = dpp_add_xor2(dpp_add_xor1(s0));
      s1v = dpp_add_xor2(dpp_add_xor1(s1v));
      s2v = dpp_add_xor2(dpp_add_xor1(s2v));
      s3v = dpp_add_xor2(dpp_add_xor1(s3v));
      float my = (qk == 0) ? s0 : (qk == 1) ? s1v : (qk == 2) ? s2v : s3v;
      yct[sn][((tid & 127) << 2) + (tid >> 7)] = my;   // [j][gate], one 8-way write
    } else if (wv == 6) {
      // stage ghi4 for this step's gates
      float4 e0, e1;
      e0.x = gr[0] + bhh6[0]; e0.y = gr[1] + bhh6[1]; e0.z = gr[2]; e0.w = bhh6[2];
      e1.x = gr[3] + bhh6[3]; e1.y = gr[4] + bhh6[4]; e1.z = gr[5]; e1.w = bhh6[5];
      ((float4*)ghi4)[lane] = e0;
      ((float4*)ghi4)[64 + lane] = e1;
      if (t + 2 <= 511) {   // 2-deep prefetch into the set just consumed
        size_t bp = ((size_t)b * 512 + t + 2) * 384;
        gr[0] = gi_glob[bp + lane];      gr[1] = gi_glob[bp + 128 + lane]; gr[2] = gi_glob[bp + 256 + lane];
        gr[3] = gi_glob[bp + 64 + lane]; gr[4] = gi_glob[bp + 192 + lane]; gr[5] = gi_glob[bp + 320 + lane];
      }
      {
        int m = lane >> 1, kc = lane & 1;
        float ax = 0.f, ay = 0.f, az = 0.f, aw = 0.f;
        #pragma unroll
        for (int c = 0; c < 16; c++) {
          float4 o4 = ((const float4*)obs)[16 * kc + c];
          ax += w1reg[c].x * o4.x; ay += w1reg[c].y * o4.y;
          az += w1reg[c].z * o4.z; aw += w1reg[c].w * o4.w;
        }
        float d = (ax + ay) + (az + aw);
        d = dpp_add_xor1(d);
        if (kc == 0) z1buf[m] = ftanh_(d + b1s[m]);
      }
      if (lane < 40) {
        int a = lane >> 2, k2 = lane & 3;
        int m0 = 8 * k2;
        float4 z4a = ((const float4*)(z1buf + m0))[0], z4b = ((const float4*)(z1buf + m0))[1];
        float4 wa = ((const float4*)(&w2buf[a][m0]))[0], wb = ((const float4*)(&w2buf[a][m0]))[1];
        float p = z4a.x * wa.x + z4a.y * wa.y + z4a.z * wa.z + z4a.w * wa.w
                + z4b.x * wb.x + z4b.y * wb.y + z4b.z * wb.z + z4b.w * wb.w;
        p = dpp_add_xor2(dpp_add_xor1(p));
        if (k2 == 0) pl2[a].x = p + b2s[a];
      }
      {  // osum half: j = lane (9 oldest ring entries, same fp order as before)
        int bs = tmod + 1; if (bs >= 10) bs -= 10;
        float s = 0.f;
        #pragma unroll
        for (int a = 0; a < 9; a++) s += ring2[bs + a][lane];
        osum[lane] = s;
      }
    } else { // wv == 7
      if (lane < 10) g1buf[lane] = g1r;
      if (lane == 12) a2s_lds = a2r;
      if (t + 2 <= 511) {
        if (lane < 10) g1r = g1_tab[((size_t)(t + 1) * 256 + b) * 10 + lane];
        if (lane == 12) a2r = a2_tab[(size_t)(t + 1) * 256 + b];
      }
      {
        int m = 32 + (lane >> 1), kc = lane & 1;
        float ax = 0.f, ay = 0.f, az = 0.f, aw = 0.f;
        #pragma unroll
        for (int c = 0; c < 16; c++) {
          float4 o4 = ((const float4*)obs)[16 * kc + c];
          ax += w1reg[c].x * o4.x; ay += w1reg[c].y * o4.y;
          az += w1reg[c].z * o4.z; aw += w1reg[c].w * o4.w;
        }
        float d = (ax + ay) + (az + aw);
        d = dpp_add_xor1(d);
        if (kc == 0) z1buf[m] = ftanh_(d + b1s[m]);
      }
      if (lane < 40) {
        int a = lane >> 2, k2 = lane & 3;
        int m0 = 32 + 8 * k2;
        float4 z4a = ((const float4*)(z1buf + m0))[0], z4b = ((const float4*)(z1buf + m0))[1];
        float4 wa = ((const float4*)(&w2buf[a][m0]))[0], wb = ((const float4*)(&w2buf[a][m0]))[1];
        float p = z4a.x * wa.x + z4a.y * wa.y + z4a.z * wa.z + z4a.w * wa.w
                + z4b.x * wb.x + z4b.y * wb.y + z4b.z * wb.z + z4b.w * wb.w;
        p = dpp_add_xor2(dpp_add_xor1(p));
        if (k2 == 0) pl2[a].y = p + g1buf[a];
      }
      {  // osum half: j = 64+lane
        int bs = tmod + 1; if (bs >= 10) bs -= 10;
        float s = 0.f;
        #pragma unroll
        for (int a = 0; a < 9; a++) s += ring2[bs + a][64 + lane];
        osum[64 + lane] = s;
      }
    }
    bar_lds();   // yct/ghi4/pl2/a2s/osum ready

    // -------- phase 2: gates on waves 0-3 x 32 lanes (one per SIMD) --------
    if (wv < 4 && lane < 32) {
      const int j = (wv << 5) + lane;
      float4 p0 = ((const float4*)pl2)[0];
      float4 p1 = ((const float4*)pl2)[1];
      float4 p2 = ((const float4*)pl2)[2];
      float4 p3 = ((const float4*)pl2)[3];
      float4 p4 = ((const float4*)pl2)[4];
      int a2v = a2s_lds;
      float l[10] = {p0.x + p0.y, p0.z + p0.w, p1.x + p1.y, p1.z + p1.w, p2.x + p2.y,
                     p2.z + p2.w, p3.x + p3.y, p3.z + p3.w, p4.x + p4.y, p4.z + p4.w};
      float best = l[0]; int bi = 0;
      #pragma unroll
      for (int a = 1; a < 10; a++) { if (l[a] > best) { best = l[a]; bi = a; } }
      int s1 = tmod + bi;  if (s1 >= 10) s1 -= 10;
      int s2 = tmod + a2v; if (s2 >= 10) s2 -= 10;
      float4 y1 = *(const float4*)(&yct[s1][j << 2]);
      float4 y2 = *(const float4*)(&yct[s2][j << 2]);
      float4 yn = *(const float4*)(&yct[sn][j << 2]);
      float4 gv = ((const float4*)ghi4)[j];
      float gh1 = 0.5f * (0.5f * (y1.x + y2.x)) + 0.5f * yn.x;
      float gh2 = 0.5f * (0.5f * (y1.y + y2.y)) + 0.5f * yn.y;
      float gh3 = gv.w + 0.5f * (0.5f * (y1.z + y2.z)) + 0.5f * yn.z;
      float r  = fsigmoid(gv.x + gh1);
      float zz = fsigmoid(gv.y + gh2);
      float n  = ftanh_(gv.z + r * gh3);
      float hw = 0.5f * ((ring2[s1][j] + ring2[s2][j]) * 0.5f) + 0.5f * hprev;
      float hnew = (1.0f - zz) * n + zz * hw;
      hbuf[j] = hnew;
      ring2[tmod][j] = hnew;
      ring2[tmod + 10][j] = hnew;
      obs[j] = (osum[j] + hnew) / 10.0f;
      out[BH_ + ((size_t)b * 512 + t) * 128 + j] = hnew;
      if (t == last) out[(size_t)b * H_ + j] = hnew;
      hprev = hnew;
    }
    bar_lds();   // hbuf/ring2/obs ready for next step
    tmod = (tmod == 9) ? 0 : tmod + 1;
  };

  // ---- t = 1..511, unrolled by 2 so prefetch reg sets have static names ----
  #pragma unroll 1
  for (int t = 1; t < 511; t += 2) {
    step(t, gA, g1A, a2A);
    step(t + 1, gB, g1B, a2B);
  }
  step(511, gA, g1A, a2A);
}

extern "C" void kernel_launch(void* const* d_in, const int* in_sizes, int n_in,
                              void* d_out, int out_size, void* d_ws, size_t ws_size,
                              hipStream_t stream) {
  (void)in_sizes; (void)n_in; (void)out_size; (void)ws_size;
  const float* x     = (const float*)d_in[0];
  const int*   mask  = (const int*)d_in[1];
  const float* w_ih  = (const float*)d_in[2];
  const float* w_hh  = (const float*)d_in[3];
  const float* b_ih  = (const float*)d_in[4];
  const float* b_hh  = (const float*)d_in[5];
  const float* a1w1  = (const float*)d_in[6];
  const float* a1b1  = (const float*)d_in[7];
  const float* a1w2  = (const float*)d_in[8];
  const float* a1b2  = (const float*)d_in[9];
  const float* a2w1  = (const float*)d_in[10];
  const float* a2b1  = (const float*)d_in[11];
  const float* a2w2  = (const float*)d_in[12];
  const float* a2b2  = (const float*)d_in[13];
  float* out = (float*)d_out;

  // workspace: gi (201.3 MB) | g1 (5.2 MB) | keys | a2_tab | z table (33.5 MB)
  float*    gi       = (float*)d_ws;
  float*    g1       = gi + (size_t)131072 * 384;
  unsigned* keys_tab = (unsigned*)(g1 + NG);
  int*      a2_tab   = (int*)(keys_tab + 2048);
  float*    zt       = (float*)(a2_tab + 130816);

  p0_keys<<<4, 256, 0, stream>>>(keys_tab);
  gemm_tiled<<<3584, 256, 0, stream>>>(x, w_ih, b_ih, a2w1, a2b1, gi, zt);
  sampler<<<511, 256, 0, stream>>>(zt, a2w2, a2b2, keys_tab, g1, a2_tab);
  seq_kernel<<<256, 512, 0, stream>>>(gi, mask, w_hh, b_hh,
                                      a1w1, a1b1, a1w2, a1b2, g1, a2_tab, out);
}

// Round 3
// 1064.330 us; speedup vs baseline: 1.4750x; 1.4750x over previous
//
#include <hip/hip_runtime.h>
#include <math.h>

// Problem constants: B=256, T=512, D=128, H=128 (3H=384), U=64, A=10, LAMDA=0.5
#define B_ 256
#define T_ 512
#define D_ 128
#define H_ 128
#define BH_ 32768      // B_*H_
#define NG 1308160     // 511*256*10 gumbels per agent

// LDS-ordering-only barrier: skips the vmcnt(0) drain __syncthreads() forces.
__device__ __forceinline__ void bar_lds() {
  asm volatile("s_waitcnt lgkmcnt(0)\n\ts_barrier" ::: "memory");
}

// quad reductions on the VALU pipe (DPP), not the LDS pipe
__device__ __forceinline__ float dpp_add_xor1(float v) {
  int r = __builtin_amdgcn_update_dpp(0, __float_as_int(v), 0xB1, 0xF, 0xF, true);
  return v + __int_as_float(r);
}
__device__ __forceinline__ float dpp_add_xor2(float v) {
  int r = __builtin_amdgcn_update_dpp(0, __float_as_int(v), 0x4E, 0xF, 0xF, true);
  return v + __int_as_float(r);
}

// fast transcendentals (v_exp/v_rcp based, no div, no branches; ~3 ulp)
__device__ __forceinline__ float frcp(float x) { return __builtin_amdgcn_rcpf(x); }
__device__ __forceinline__ float fsigmoid(float x) { return frcp(1.0f + __expf(-x)); }
__device__ __forceinline__ float ftanh_(float x) { return 1.0f - 2.0f * frcp(1.0f + __expf(2.0f * x)); }

// ---------------- threefry2x32 (exact JAX semantics) ----------------
__device__ __forceinline__ void tf2x32(unsigned k0, unsigned k1, unsigned x0, unsigned x1,
                                       unsigned& o0, unsigned& o1) {
  unsigned k2 = k0 ^ k1 ^ 0x1BD11BDAu;
  unsigned v0 = x0 + k0, v1 = x1 + k1;
#define TFR(r) { v0 += v1; v1 = (v1 << (r)) | (v1 >> (32 - (r))); v1 ^= v0; }
  TFR(13) TFR(15) TFR(26) TFR(6)   v0 += k1; v1 += k2 + 1u;
  TFR(17) TFR(29) TFR(16) TFR(24)  v0 += k2; v1 += k0 + 2u;
  TFR(13) TFR(15) TFR(26) TFR(6)   v0 += k0; v1 += k1 + 3u;
  TFR(17) TFR(29) TFR(16) TFR(24)  v0 += k1; v1 += k2 + 4u;
  TFR(13) TFR(15) TFR(26) TFR(6)   v0 += k2; v1 += k0 + 5u;
#undef TFR
  o0 = v0; o1 = v1;
}

__device__ __forceinline__ float gumbel_f(unsigned bits) {
  const float tiny = 1.17549435e-38f;
  float u = __uint_as_float((bits >> 9) | 0x3f800000u) - 1.0f;
  u = u + tiny;
  u = fmaxf(tiny, u);
  return -__logf(-__logf(u));
}

// ---------------- P0: split keys (jax_threefry_partitionable=True) ----------------
__global__ void p0_keys(unsigned* __restrict__ keys_tab) {
  int i = blockIdx.x * blockDim.x + threadIdx.x;
  if (i >= 1024) return;
  unsigned o0, o1;
  tf2x32(0u, 42u, 0u, (unsigned)i, o0, o1);
  keys_tab[2 * i] = o0; keys_tab[2 * i + 1] = o1;
}

// ---------------- G: tiled fp32 GEMM, N=448 (384 gi cols + 64 a2-hidden cols) ----------
// Block tile 256m x 64n, 256 threads, micro 16m x 4n, K staged in 4 chunks of 32.
// nb==6 reads a2w1/a2b1, applies fast tanh, writes z table [M][64].
#define SX 264
#define SW 72
__global__ __launch_bounds__(256, 4) void gemm_tiled(
    const float* __restrict__ x, const float* __restrict__ w_ih,
    const float* __restrict__ b_ih, const float* __restrict__ a2w1,
    const float* __restrict__ a2b1, float* __restrict__ gi, float* __restrict__ zt) {
  __shared__ __align__(16) float Xs[32 * SX];
  __shared__ __align__(16) float Ws[32 * SW];
  const int tid = threadIdx.x;
  const int mb = blockIdx.x & 511;          // 512 m-tiles
  const int nb = blockIdx.x >> 9;           // 0..6
  const bool isz = (nb == 6);
  const size_t m0 = (size_t)mb * 256;
  const int n0 = isz ? 0 : nb * 64;
  const float* wsrc = isz ? a2w1 : w_ih;
  const float* bsrc = isz ? a2b1 : b_ih;
  const int mt = tid >> 4;                  // 0..15 -> rows mt*16..+15
  const int nt = tid & 15;                  // 0..15 -> cols nt*4..+3
  const int kg = tid >> 5;                  // staging: k-group 0..7
  const int ri = tid & 31;                  // staging: row-in-pass

  float acc[16][4];
  #pragma unroll
  for (int i = 0; i < 16; i++)
    #pragma unroll
    for (int j = 0; j < 4; j++) acc[i][j] = 0.f;

  #pragma unroll 1
  for (int kc = 0; kc < 4; kc++) {
    const int k0 = kc * 32;
    __syncthreads();
    #pragma unroll
    for (int p = 0; p < 8; p++) {
      int row = ri + 32 * p;
      float4 v = *(const float4*)(x + (m0 + row) * 128 + k0 + 4 * kg);
      Xs[(4 * kg + 0) * SX + row] = v.x;
      Xs[(4 * kg + 1) * SX + row] = v.y;
      Xs[(4 * kg + 2) * SX + row] = v.z;
      Xs[(4 * kg + 3) * SX + row] = v.w;
    }
    #pragma unroll
    for (int p = 0; p < 2; p++) {
      int n = ri + 32 * p;
      float4 v = *(const float4*)(wsrc + (size_t)(n0 + n) * 128 + k0 + 4 * kg);
      Ws[(4 * kg + 0) * SW + n] = v.x;
      Ws[(4 * kg + 1) * SW + n] = v.y;
      Ws[(4 * kg + 2) * SW + n] = v.z;
      Ws[(4 * kg + 3) * SW + n] = v.w;
    }
    __syncthreads();
    #pragma unroll 4
    for (int kk = 0; kk < 32; kk++) {
      const float* xrow = Xs + kk * SX + mt * 16;
      float4 xa0 = ((const float4*)xrow)[0];
      float4 xa1 = ((const float4*)xrow)[1];
      float4 xa2 = ((const float4*)xrow)[2];
      float4 xa3 = ((const float4*)xrow)[3];
      float4 wv = *(const float4*)(Ws + kk * SW + nt * 4);
      float xv[16] = {xa0.x, xa0.y, xa0.z, xa0.w, xa1.x, xa1.y, xa1.z, xa1.w,
                      xa2.x, xa2.y, xa2.z, xa2.w, xa3.x, xa3.y, xa3.z, xa3.w};
      #pragma unroll
      for (int i = 0; i < 16; i++) {
        acc[i][0] += xv[i] * wv.x;
        acc[i][1] += xv[i] * wv.y;
        acc[i][2] += xv[i] * wv.z;
        acc[i][3] += xv[i] * wv.w;
      }
    }
  }
  float4 bias = *(const float4*)(bsrc + n0 + nt * 4);
  if (!isz) {
    #pragma unroll
    for (int i = 0; i < 16; i++) {
      float4 o;
      o.x = acc[i][0] + bias.x; o.y = acc[i][1] + bias.y;
      o.z = acc[i][2] + bias.z; o.w = acc[i][3] + bias.w;
      size_t m = m0 + (size_t)mt * 16 + i;
      *(float4*)(gi + m * 384 + n0 + nt * 4) = o;
    }
  } else {
    #pragma unroll
    for (int i = 0; i < 16; i++) {
      float4 o;
      o.x = ftanh_(acc[i][0] + bias.x); o.y = ftanh_(acc[i][1] + bias.y);
      o.z = ftanh_(acc[i][2] + bias.z); o.w = ftanh_(acc[i][3] + bias.w);
      size_t m = m0 + (size_t)mt * 16 + i;
      *(float4*)(zt + m * 64 + nt * 4) = o;
    }
  }
}

// ---------------- SAMP: a2 logits+gumbel+argmax AND g1 gumbel table ----------------
// block = one t (511 blocks); wave per sample, z prefetch pipelined.
// w2s padded to [10][68]: row stride 64 put all 10 'a' rows on the same banks
// (a*64 % 32 == 0) -> 10-way conflict on the dot; stride 68 -> spread across banks.
__global__ __launch_bounds__(256) void sampler(
    const float* __restrict__ zt, const float* __restrict__ w2,
    const float* __restrict__ b2, const unsigned* __restrict__ keys_tab,
    float* __restrict__ g1, int* __restrict__ a2_tab) {
  __shared__ __align__(16) float w2s[10][68];
  __shared__ float b2s[10];
  __shared__ __align__(16) float zs[4][64];
  const int tid = threadIdx.x, w = tid >> 6, lane = tid & 63;
  const int t = blockIdx.x + 1;
  for (int i = tid; i < 640; i += 256) w2s[i >> 6][i & 63] = w2[i];
  if (tid < 10) b2s[tid] = b2[tid];
  __syncthreads();
  const unsigned k0a = keys_tab[2 * (2 * t + 1)], k1a = keys_tab[2 * (2 * t + 1) + 1];
  const unsigned k0g = keys_tab[2 * (2 * t)],     k1g = keys_tab[2 * (2 * t) + 1];
  const int a = lane & 15, kc = lane >> 4;
  float zr = zt[((size_t)w * 512 + t) * 64 + lane];   // b = w (it=0)
  #pragma unroll 1
  for (int it = 0; it < 64; it++) {
    const int b = 4 * it + w;
    zs[w][lane] = zr;
    if (it < 63) zr = zt[((size_t)(b + 4) * 512 + t) * 64 + lane];
    float p = 0.f;
    if (a < 10) {
      const float4* zp = (const float4*)(&zs[w][16 * kc]);
      const float4* wp = (const float4*)(&w2s[a][16 * kc]);
      #pragma unroll
      for (int c = 0; c < 4; c++) {
        float4 zv = zp[c], w4 = wp[c];
        p += w4.x * zv.x + w4.y * zv.y + w4.z * zv.z + w4.w * zv.w;
      }
    }
    p += __shfl_xor(p, 16);
    p += __shfl_xor(p, 32);
    float val = -3.0e38f;
    if (a < 10 && kc == 0) {
      unsigned o0, o1;
      tf2x32(k0a, k1a, 0u, (unsigned)(b * 10 + a), o0, o1);
      val = (p + b2s[a]) + gumbel_f(o0 ^ o1);
      tf2x32(k0g, k1g, 0u, (unsigned)(b * 10 + a), o0, o1);
      g1[((size_t)(t - 1) * 256 + b) * 10 + a] = gumbel_f(o0 ^ o1);
    }
    float best = 0.f; int bi = 0;
    #pragma unroll
    for (int aa = 0; aa < 10; aa++) {
      float v = __shfl(val, aa);
      if (aa == 0 || v > best) { best = v; bi = aa; }
    }
    if (lane == 0) a2_tab[(size_t)(t - 1) * 256 + b] = bi;
  }
}

// ---------------- S: sequential per-batch kernel (1 block = 1 batch elem) ----------------
// Round-0 structure (proven 763 us) + two surgical changes:
//  - w2buf padded [10][68]: kills the 10-way bank conflict in the a1 logits dot
//    (a*64 % 32 == 0 put all rows on bank 0; 1.99e7 conflict cycles measured)
//  - osum (sum of 9 oldest ring entries) produced by waves 2/3 in phase 1
//    (issue-bound matvec waves; hides in wave-6/7 latency stalls) so the gate
//    phase's obs update is 1 LDS read instead of a 9-read dependent chain.
//    Summation order identical: osum = ring[base]..ring[base+8] ascending.
__global__ __launch_bounds__(512, 2) void seq_kernel(
    const float* __restrict__ gi_glob, const int* __restrict__ mask,
    const float* __restrict__ w_hh, const float* __restrict__ b_hh,
    const float* __restrict__ a1w1, const float* __restrict__ a1b1,
    const float* __restrict__ a1w2, const float* __restrict__ a1b2,
    const float* __restrict__ g1_tab, const int* __restrict__ a2_tab,
    float* __restrict__ out) {
  __shared__ __align__(16) float ring2[20][128];  // doubled ring: h_s at [s%10] and [s%10+10]
  __shared__ __align__(16) float yc[10][384];     // yc[s] = W_hh · ring[s]
  __shared__ __align__(16) float hbuf[128];       // h_{t-1}
  __shared__ __align__(16) float ghi[384];        // staged gi[b][t] (+b_hh on rows 0..255)
  __shared__ __align__(16) float obs[128];        // mean of ring (finalized in gates phase)
  __shared__ __align__(16) float osum[128];       // sum of 9 oldest ring entries (waves 2/3)
  __shared__ __align__(16) float z1buf[64];
  __shared__ __align__(16) float lastbuf[128];
  __shared__ __align__(16) float w2buf[10][68];   // padded (bank conflicts)
  __shared__ float bhh3s[128];                    // b_hh rows 256..383 (n-gate)
  __shared__ float b1s[64], b2s[10];
  __shared__ float g1buf[10];
  __shared__ float2 pl2[16];
  __shared__ int a2s_lds;
  __shared__ int redi[8];
  __shared__ int last_s;

  const int tid = threadIdx.x;
  const int wave = tid >> 6, lane = tid & 63;
  const int b = blockIdx.x;

  // ---- register-resident W_hh for waves 0-5: rows 4q+i, k-quad qk ----
  float4 wr[4][8];
  const int q = tid >> 2, qk = tid & 3;
  if (tid < 384) {
    #pragma unroll
    for (int i = 0; i < 4; i++) {
      const float* basep = w_hh + (size_t)(4 * q + i) * 128 + 4 * qk;
      #pragma unroll
      for (int c = 0; c < 8; c++) wr[i][c] = *(const float4*)(basep + 16 * c);
    }
  }
  // ---- register-resident a1w1 for waves 6/7 ----
  float4 w1reg[16];
  float4 bhh4a = make_float4(0.f, 0.f, 0.f, 0.f);
  if (wave >= 6) {
    int m = ((wave - 6) << 5) + (lane >> 1);
    int kc = lane & 1;
    const float4* wp = (const float4*)(a1w1 + (size_t)m * 128 + 64 * kc);
    #pragma unroll
    for (int c = 0; c < 16; c++) w1reg[c] = wp[c];
  }
  if (wave == 6) bhh4a = ((const float4*)b_hh)[lane];   // rows 4*lane..+3 (0..255)

  // ---- LDS init ----
  for (int idx = tid; idx < 2560; idx += 512) ((float*)ring2)[idx] = 0.f;
  for (int idx = tid; idx < 3840; idx += 512) ((float*)yc)[idx] = 0.f;
  for (int idx = tid; idx < 640; idx += 512) w2buf[idx >> 6][idx & 63] = a1w2[idx];
  if (tid < 128) bhh3s[tid] = b_hh[256 + tid];
  if (tid < 64) b1s[tid] = a1b1[tid];
  if (tid < 10) b2s[tid] = a1b2[tid];
  int mv = mask[(size_t)b * T_ + tid];
  #pragma unroll
  for (int off = 1; off < 64; off <<= 1) mv += __shfl_xor(mv, off);
  if (lane == 0) redi[wave] = mv;
  const float4* gi4 = (const float4*)gi_glob;
  float4 gir0 = make_float4(0.f, 0.f, 0.f, 0.f), gir1 = gir0;
  if (wave == 6) {
    size_t base1 = ((size_t)b * 512 + 1) * 96;
    gir0 = gi4[base1 + lane];
    if (lane < 32) gir1 = gi4[base1 + 64 + lane];
  }
  float g1r = 0.f; int a2r = 0;
  if (wave == 7 && lane < 10) g1r = g1_tab[(size_t)b * 10 + lane];
  if (wave == 7 && lane == 12) a2r = a2_tab[b];
  __syncthreads();
  if (tid == 0) {
    int s = 0;
    #pragma unroll
    for (int w = 0; w < 8; w++) s += redi[w];
    last_s = s - 1;
  }
  __syncthreads();
  const int last = last_s;

  // ---- t = 0: h0 = gru(x0, 0); obs for t=1 ----
  if (tid < 128) {
    int j = tid;
    const float* g0 = gi_glob + (size_t)b * 512 * 384;
    float r  = fsigmoid(g0[j] + b_hh[j]);
    float zz = fsigmoid(g0[128 + j] + b_hh[128 + j]);
    float n  = ftanh_(g0[256 + j] + r * b_hh[256 + j]);
    float hnew = (1.0f - zz) * n;
    hbuf[j] = hnew; ring2[0][j] = hnew; ring2[10][j] = hnew;
    obs[j] = hnew / 10.0f;
    out[BH_ + ((size_t)b * 512) * 128 + j] = hnew;
    if (0 == last) lastbuf[j] = hnew;
  }
  __syncthreads();

  // ---- t = 1..511 ----
  #pragma unroll 1
  for (int t = 1; t < T_; t++) {
    const int sn = (t + 9) % 10;   // slot of h_{t-1}
    if (tid < 384) {
      // ---- yc[sn] = W_hh · h_{t-1}, rows 4q..4q+3 ----
      const float4* hb4 = (const float4*)hbuf;
      float4 a0 = make_float4(0.f, 0.f, 0.f, 0.f), a1v = a0, a2v = a0, a3v = a0;
      #pragma unroll
      for (int c = 0; c < 8; c++) {
        float4 h4 = hb4[4 * c + qk];
        a0.x += wr[0][c].x * h4.x; a0.y += wr[0][c].y * h4.y; a0.z += wr[0][c].z * h4.z; a0.w += wr[0][c].w * h4.w;
        a1v.x += wr[1][c].x * h4.x; a1v.y += wr[1][c].y * h4.y; a1v.z += wr[1][c].z * h4.z; a1v.w += wr[1][c].w * h4.w;
        a2v.x += wr[2][c].x * h4.x; a2v.y += wr[2][c].y * h4.y; a2v.z += wr[2][c].z * h4.z; a2v.w += wr[2][c].w * h4.w;
        a3v.x += wr[3][c].x * h4.x; a3v.y += wr[3][c].y * h4.y; a3v.z += wr[3][c].z * h4.z; a3v.w += wr[3][c].w * h4.w;
      }
      float s0  = (a0.x + a0.y) + (a0.z + a0.w);
      float s1v = (a1v.x + a1v.y) + (a1v.z + a1v.w);
      float s2v = (a2v.x + a2v.y) + (a2v.z + a2v.w);
      float s3v = (a3v.x + a3v.y) + (a3v.z + a3v.w);
      s0  = dpp_add_xor2(dpp_add_xor1(s0));
      s1v = dpp_add_xor2(dpp_add_xor1(s1v));
      s2v = dpp_add_xor2(dpp_add_xor1(s2v));
      s3v = dpp_add_xor2(dpp_add_xor1(s3v));
      float my = (qk == 0) ? s0 : (qk == 1) ? s1v : (qk == 2) ? s2v : s3v;
      yc[sn][4 * q + qk] = my;        // addr = tid -> conflict-free
      // ---- waves 2/3: 9-entry ring sum for this step's obs update ----
      // Issue-bound waves; these conflict-free reads hide under wave-6/7 latency.
      if (tid >= 128 && tid < 256) {
        int j = tid - 128;
        int bs = (t + 1) % 10;
        float s = 0.f;
        #pragma unroll
        for (int a = 0; a < 9; a++) s += ring2[bs + a][j];
        osum[j] = s;
      }
    } else if (wave == 6) {
      float4 g0 = gir0;
      g0.x += bhh4a.x; g0.y += bhh4a.y; g0.z += bhh4a.z; g0.w += bhh4a.w;
      ((float4*)ghi)[lane] = g0;
      if (lane < 32) ((float4*)ghi)[64 + lane] = gir1;
      if (t < 511) {
        size_t basep = ((size_t)b * 512 + t + 1) * 96;
        gir0 = gi4[basep + lane];
        if (lane < 32) gir1 = gi4[basep + 64 + lane];
      }
      {
        int m = lane >> 1, kc = lane & 1;
        float ax = 0.f, ay = 0.f, az = 0.f, aw = 0.f;
        #pragma unroll
        for (int c = 0; c < 16; c++) {
          float4 o4 = ((const float4*)obs)[16 * kc + c];
          ax += w1reg[c].x * o4.x; ay += w1reg[c].y * o4.y;
          az += w1reg[c].z * o4.z; aw += w1reg[c].w * o4.w;
        }
        float d = (ax + ay) + (az + aw);
        d = dpp_add_xor1(d);
        if (kc == 0) z1buf[m] = ftanh_(d + b1s[m]);
      }
      if (lane < 40) {
        int a = lane >> 2, k2 = lane & 3;
        int m0 = 8 * k2;
        float4 z4a = ((const float4*)(z1buf + m0))[0], z4b = ((const float4*)(z1buf + m0))[1];
        float4 wa = ((const float4*)(&w2buf[a][m0]))[0], wb = ((const float4*)(&w2buf[a][m0]))[1];
        float p = z4a.x * wa.x + z4a.y * wa.y + z4a.z * wa.z + z4a.w * wa.w
                + z4b.x * wb.x + z4b.y * wb.y + z4b.z * wb.z + z4b.w * wb.w;
        p = dpp_add_xor2(dpp_add_xor1(p));
        if (k2 == 0) pl2[a].x = p + b2s[a];
      }
    } else { // wave 7
      if (lane < 10) g1buf[lane] = g1r;
      if (lane == 12) a2s_lds = a2r;
      if (t < 511) {
        if (lane < 10) g1r = g1_tab[((size_t)t * 256 + b) * 10 + lane];
        if (lane == 12) a2r = a2_tab[(size_t)t * 256 + b];
      }
      {
        int m = 32 + (lane >> 1), kc = lane & 1;
        float ax = 0.f, ay = 0.f, az = 0.f, aw = 0.f;
        #pragma unroll
        for (int c = 0; c < 16; c++) {
          float4 o4 = ((const float4*)obs)[16 * kc + c];
          ax += w1reg[c].x * o4.x; ay += w1reg[c].y * o4.y;
          az += w1reg[c].z * o4.z; aw += w1reg[c].w * o4.w;
        }
        float d = (ax + ay) + (az + aw);
        d = dpp_add_xor1(d);
        if (kc == 0) z1buf[m] = ftanh_(d + b1s[m]);
      }
      if (lane < 40) {
        int a = lane >> 2, k2 = lane & 3;
        int m0 = 32 + 8 * k2;
        float4 z4a = ((const float4*)(z1buf + m0))[0], z4b = ((const float4*)(z1buf + m0))[1];
        float4 wa = ((const float4*)(&w2buf[a][m0]))[0], wb = ((const float4*)(&w2buf[a][m0]))[1];
        float p = z4a.x * wa.x + z4a.y * wa.y + z4a.z * wa.z + z4a.w * wa.w
                + z4b.x * wb.x + z4b.y * wb.y + z4b.z * wb.z + z4b.w * wb.w;
        p = dpp_add_xor2(dpp_add_xor1(p));
        if (k2 == 0) pl2[a].y = p + g1buf[a];
      }
    }
    bar_lds();   // ycache/ghi/pl2/a2s/osum ready

    if (tid < 128) {
      float best = 0.f; int bi = 0;
      #pragma unroll
      for (int a = 0; a < 10; a++) {
        float2 pv = pl2[a];
        float v = pv.x + pv.y;
        if (a == 0 || v > best) { best = v; bi = a; }
      }
      const int s1 = (t + bi) % 10;
      const int s2 = (t + a2s_lds) % 10;
      int j = tid;
      float gh1 = 0.5f * (0.5f * (yc[s1][j]       + yc[s2][j]))       + 0.5f * yc[sn][j];
      float gh2 = 0.5f * (0.5f * (yc[s1][128 + j] + yc[s2][128 + j])) + 0.5f * yc[sn][128 + j];
      float gh3 = bhh3s[j] + 0.5f * (0.5f * (yc[s1][256 + j] + yc[s2][256 + j])) + 0.5f * yc[sn][256 + j];
      float r  = fsigmoid(ghi[j] + gh1);
      float zz = fsigmoid(ghi[128 + j] + gh2);
      float n  = ftanh_(ghi[256 + j] + r * gh3);
      float hw = 0.5f * ((ring2[s1][j] + ring2[s2][j]) * 0.5f) + 0.5f * hbuf[j];
      float hnew = (1.0f - zz) * n + zz * hw;
      hbuf[j] = hnew;
      ring2[t % 10][j] = hnew;
      ring2[t % 10 + 10][j] = hnew;
      out[BH_ + ((size_t)b * 512 + t) * 128 + j] = hnew;   // direct h store
      if (t == last) lastbuf[j] = hnew;
      obs[j] = (osum[j] + hnew) / 10.0f;   // osum precomputed by waves 2/3
    }
    bar_lds();   // hbuf/ring2/obs ready for next step
  }
  if (tid < 128) out[(size_t)b * H_ + tid] = lastbuf[tid];
}

extern "C" void kernel_launch(void* const* d_in, const int* in_sizes, int n_in,
                              void* d_out, int out_size, void* d_ws, size_t ws_size,
                              hipStream_t stream) {
  (void)in_sizes; (void)n_in; (void)out_size; (void)ws_size;
  const float* x     = (const float*)d_in[0];
  const int*   mask  = (const int*)d_in[1];
  const float* w_ih  = (const float*)d_in[2];
  const float* w_hh  = (const float*)d_in[3];
  const float* b_ih  = (const float*)d_in[4];
  const float* b_hh  = (const float*)d_in[5];
  const float* a1w1  = (const float*)d_in[6];
  const float* a1b1  = (const float*)d_in[7];
  const float* a1w2  = (const float*)d_in[8];
  const float* a1b2  = (const float*)d_in[9];
  const float* a2w1  = (const float*)d_in[10];
  const float* a2b1  = (const float*)d_in[11];
  const float* a2w2  = (const float*)d_in[12];
  const float* a2b2  = (const float*)d_in[13];
  float* out = (float*)d_out;

  // workspace: gi (201.3 MB) | g1 (5.2 MB) | keys | a2_tab | z table (33.5 MB)
  float*    gi       = (float*)d_ws;
  float*    g1       = gi + (size_t)131072 * 384;
  unsigned* keys_tab = (unsigned*)(g1 + NG);
  int*      a2_tab   = (int*)(keys_tab + 2048);
  float*    zt       = (float*)(a2_tab + 130816);

  p0_keys<<<4, 256, 0, stream>>>(keys_tab);
  gemm_tiled<<<3584, 256, 0, stream>>>(x, w_ih, b_ih, a2w1, a2b1, gi, zt);
  sampler<<<511, 256, 0, stream>>>(zt, a2w2, a2b2, keys_tab, g1, a2_tab);
  seq_kernel<<<256, 512, 0, stream>>>(gi, mask, w_hh, b_hh,
                                      a1w1, a1b1, a1w2, a1b2, g1, a2_tab, out);
}

// Round 4
// 1044.703 us; speedup vs baseline: 1.5028x; 1.0188x over previous
//
#include <hip/hip_runtime.h>
#include <math.h>

// Problem constants: B=256, T=512, D=128, H=128 (3H=384), U=64, A=10, LAMDA=0.5
#define B_ 256
#define T_ 512
#define D_ 128
#define H_ 128
#define BH_ 32768      // B_*H_
#define NG 1308160     // 511*256*10 gumbels per agent

// LDS-ordering-only barrier: skips the vmcnt(0) drain __syncthreads() forces.
__device__ __forceinline__ void bar_lds() {
  asm volatile("s_waitcnt lgkmcnt(0)\n\ts_barrier" ::: "memory");
}

// quad reductions on the VALU pipe (DPP), not the LDS pipe
__device__ __forceinline__ float dpp_add_xor1(float v) {
  int r = __builtin_amdgcn_update_dpp(0, __float_as_int(v), 0xB1, 0xF, 0xF, true);
  return v + __int_as_float(r);
}
__device__ __forceinline__ float dpp_add_xor2(float v) {
  int r = __builtin_amdgcn_update_dpp(0, __float_as_int(v), 0x4E, 0xF, 0xF, true);
  return v + __int_as_float(r);
}

// fast transcendentals (v_exp/v_rcp based, no div, no branches; ~3 ulp)
__device__ __forceinline__ float frcp(float x) { return __builtin_amdgcn_rcpf(x); }
__device__ __forceinline__ float fsigmoid(float x) { return frcp(1.0f + __expf(-x)); }
__device__ __forceinline__ float ftanh_(float x) { return 1.0f - 2.0f * frcp(1.0f + __expf(2.0f * x)); }

// ---------------- threefry2x32 (exact JAX semantics) ----------------
__device__ __forceinline__ void tf2x32(unsigned k0, unsigned k1, unsigned x0, unsigned x1,
                                       unsigned& o0, unsigned& o1) {
  unsigned k2 = k0 ^ k1 ^ 0x1BD11BDAu;
  unsigned v0 = x0 + k0, v1 = x1 + k1;
#define TFR(r) { v0 += v1; v1 = (v1 << (r)) | (v1 >> (32 - (r))); v1 ^= v0; }
  TFR(13) TFR(15) TFR(26) TFR(6)   v0 += k1; v1 += k2 + 1u;
  TFR(17) TFR(29) TFR(16) TFR(24)  v0 += k2; v1 += k0 + 2u;
  TFR(13) TFR(15) TFR(26) TFR(6)   v0 += k0; v1 += k1 + 3u;
  TFR(17) TFR(29) TFR(16) TFR(24)  v0 += k1; v1 += k2 + 4u;
  TFR(13) TFR(15) TFR(26) TFR(6)   v0 += k2; v1 += k0 + 5u;
#undef TFR
  o0 = v0; o1 = v1;
}

__device__ __forceinline__ float gumbel_f(unsigned bits) {
  const float tiny = 1.17549435e-38f;
  float u = __uint_as_float((bits >> 9) | 0x3f800000u) - 1.0f;
  u = u + tiny;
  u = fmaxf(tiny, u);
  return -__logf(-__logf(u));
}

// ---------------- P0: split keys (jax_threefry_partitionable=True) ----------------
__global__ void p0_keys(unsigned* __restrict__ keys_tab) {
  int i = blockIdx.x * blockDim.x + threadIdx.x;
  if (i >= 1024) return;
  unsigned o0, o1;
  tf2x32(0u, 42u, 0u, (unsigned)i, o0, o1);
  keys_tab[2 * i] = o0; keys_tab[2 * i + 1] = o1;
}

// ---------------- G: tiled fp32 GEMM, N=448 (384 gi cols + 64 a2-hidden cols) ----------
// Block tile 256m x 64n, 256 threads, micro 16m x 4n, K staged in 4 chunks of 32.
// nb==6 reads a2w1/a2b1, applies fast tanh, writes z table [M][64].
#define SX 264
#define SW 72
__global__ __launch_bounds__(256, 4) void gemm_tiled(
    const float* __restrict__ x, const float* __restrict__ w_ih,
    const float* __restrict__ b_ih, const float* __restrict__ a2w1,
    const float* __restrict__ a2b1, float* __restrict__ gi, float* __restrict__ zt) {
  __shared__ __align__(16) float Xs[32 * SX];
  __shared__ __align__(16) float Ws[32 * SW];
  const int tid = threadIdx.x;
  const int mb = blockIdx.x & 511;          // 512 m-tiles
  const int nb = blockIdx.x >> 9;           // 0..6
  const bool isz = (nb == 6);
  const size_t m0 = (size_t)mb * 256;
  const int n0 = isz ? 0 : nb * 64;
  const float* wsrc = isz ? a2w1 : w_ih;
  const float* bsrc = isz ? a2b1 : b_ih;
  const int mt = tid >> 4;                  // 0..15 -> rows mt*16..+15
  const int nt = tid & 15;                  // 0..15 -> cols nt*4..+3
  const int kg = tid >> 5;                  // staging: k-group 0..7
  const int ri = tid & 31;                  // staging: row-in-pass

  float acc[16][4];
  #pragma unroll
  for (int i = 0; i < 16; i++)
    #pragma unroll
    for (int j = 0; j < 4; j++) acc[i][j] = 0.f;

  #pragma unroll 1
  for (int kc = 0; kc < 4; kc++) {
    const int k0 = kc * 32;
    __syncthreads();
    #pragma unroll
    for (int p = 0; p < 8; p++) {
      int row = ri + 32 * p;
      float4 v = *(const float4*)(x + (m0 + row) * 128 + k0 + 4 * kg);
      Xs[(4 * kg + 0) * SX + row] = v.x;
      Xs[(4 * kg + 1) * SX + row] = v.y;
      Xs[(4 * kg + 2) * SX + row] = v.z;
      Xs[(4 * kg + 3) * SX + row] = v.w;
    }
    #pragma unroll
    for (int p = 0; p < 2; p++) {
      int n = ri + 32 * p;
      float4 v = *(const float4*)(wsrc + (size_t)(n0 + n) * 128 + k0 + 4 * kg);
      Ws[(4 * kg + 0) * SW + n] = v.x;
      Ws[(4 * kg + 1) * SW + n] = v.y;
      Ws[(4 * kg + 2) * SW + n] = v.z;
      Ws[(4 * kg + 3) * SW + n] = v.w;
    }
    __syncthreads();
    #pragma unroll 4
    for (int kk = 0; kk < 32; kk++) {
      const float* xrow = Xs + kk * SX + mt * 16;
      float4 xa0 = ((const float4*)xrow)[0];
      float4 xa1 = ((const float4*)xrow)[1];
      float4 xa2 = ((const float4*)xrow)[2];
      float4 xa3 = ((const float4*)xrow)[3];
      float4 wv = *(const float4*)(Ws + kk * SW + nt * 4);
      float xv[16] = {xa0.x, xa0.y, xa0.z, xa0.w, xa1.x, xa1.y, xa1.z, xa1.w,
                      xa2.x, xa2.y, xa2.z, xa2.w, xa3.x, xa3.y, xa3.z, xa3.w};
      #pragma unroll
      for (int i = 0; i < 16; i++) {
        acc[i][0] += xv[i] * wv.x;
        acc[i][1] += xv[i] * wv.y;
        acc[i][2] += xv[i] * wv.z;
        acc[i][3] += xv[i] * wv.w;
      }
    }
  }
  float4 bias = *(const float4*)(bsrc + n0 + nt * 4);
  if (!isz) {
    #pragma unroll
    for (int i = 0; i < 16; i++) {
      float4 o;
      o.x = acc[i][0] + bias.x; o.y = acc[i][1] + bias.y;
      o.z = acc[i][2] + bias.z; o.w = acc[i][3] + bias.w;
      size_t m = m0 + (size_t)mt * 16 + i;
      *(float4*)(gi + m * 384 + n0 + nt * 4) = o;
    }
  } else {
    #pragma unroll
    for (int i = 0; i < 16; i++) {
      float4 o;
      o.x = ftanh_(acc[i][0] + bias.x); o.y = ftanh_(acc[i][1] + bias.y);
      o.z = ftanh_(acc[i][2] + bias.z); o.w = ftanh_(acc[i][3] + bias.w);
      size_t m = m0 + (size_t)mt * 16 + i;
      *(float4*)(zt + m * 64 + nt * 4) = o;
    }
  }
}

// ---------------- SAMP: a2 logits+gumbel+argmax AND g1 gumbel table ----------------
// block = one t (511 blocks); wave per sample, z prefetch pipelined.
// w2s padded to [10][68] (bank-conflict fix, kept from round 2).
__global__ __launch_bounds__(256) void sampler(
    const float* __restrict__ zt, const float* __restrict__ w2,
    const float* __restrict__ b2, const unsigned* __restrict__ keys_tab,
    float* __restrict__ g1, int* __restrict__ a2_tab) {
  __shared__ __align__(16) float w2s[10][68];
  __shared__ float b2s[10];
  __shared__ __align__(16) float zs[4][64];
  const int tid = threadIdx.x, w = tid >> 6, lane = tid & 63;
  const int t = blockIdx.x + 1;
  for (int i = tid; i < 640; i += 256) w2s[i >> 6][i & 63] = w2[i];
  if (tid < 10) b2s[tid] = b2[tid];
  __syncthreads();
  const unsigned k0a = keys_tab[2 * (2 * t + 1)], k1a = keys_tab[2 * (2 * t + 1) + 1];
  const unsigned k0g = keys_tab[2 * (2 * t)],     k1g = keys_tab[2 * (2 * t) + 1];
  const int a = lane & 15, kc = lane >> 4;
  float zr = zt[((size_t)w * 512 + t) * 64 + lane];   // b = w (it=0)
  #pragma unroll 1
  for (int it = 0; it < 64; it++) {
    const int b = 4 * it + w;
    zs[w][lane] = zr;
    if (it < 63) zr = zt[((size_t)(b + 4) * 512 + t) * 64 + lane];
    float p = 0.f;
    if (a < 10) {
      const float4* zp = (const float4*)(&zs[w][16 * kc]);
      const float4* wp = (const float4*)(&w2s[a][16 * kc]);
      #pragma unroll
      for (int c = 0; c < 4; c++) {
        float4 zv = zp[c], w4 = wp[c];
        p += w4.x * zv.x + w4.y * zv.y + w4.z * zv.z + w4.w * zv.w;
      }
    }
    p += __shfl_xor(p, 16);
    p += __shfl_xor(p, 32);
    float val = -3.0e38f;
    if (a < 10 && kc == 0) {
      unsigned o0, o1;
      tf2x32(k0a, k1a, 0u, (unsigned)(b * 10 + a), o0, o1);
      val = (p + b2s[a]) + gumbel_f(o0 ^ o1);
      tf2x32(k0g, k1g, 0u, (unsigned)(b * 10 + a), o0, o1);
      g1[((size_t)(t - 1) * 256 + b) * 10 + a] = gumbel_f(o0 ^ o1);
    }
    float best = 0.f; int bi = 0;
    #pragma unroll
    for (int aa = 0; aa < 10; aa++) {
      float v = __shfl(val, aa);
      if (aa == 0 || v > best) { best = v; bi = aa; }
    }
    if (lane == 0) a2_tab[(size_t)(t - 1) * 256 + b] = bi;
  }
}

// ---------------- S: sequential per-batch kernel (1 block = 1 batch elem) ----------------
// Round-2 structure (proven 735 us) + three surgical changes:
//  - nontemporal `out` stores: the 67 MB h_all stream was evicting the 201 MB gi
//    table from L3 (FETCH 113 MB -> ~56% miss, ~900cy exposure on wave 6's prefetch)
//  - fused LDS records: slotrec[10][512] = {yc_r, yc_z, yc_n, h} per j, and
//    ghi4[512] = {gi_r+bhh_r, gi_z+bhh_z, gi_n, bhh_n} per j. Phase 2 goes from
//    ~21 scattered b32 reads to 3x b128 (slots) + 1x b128 (ghi) + 1x b32 (osum).
//  - s_setprio(1) around wave 6/7 phase-1 work (latency-chain waves share SIMDs
//    with issue-bound matvec waves -> priority shortens the critical chain).
// All floating-point orderings identical to round 2.
__global__ __launch_bounds__(512, 2) void seq_kernel(
    const float* __restrict__ gi_glob, const int* __restrict__ mask,
    const float* __restrict__ w_hh, const float* __restrict__ b_hh,
    const float* __restrict__ a1w1, const float* __restrict__ a1b1,
    const float* __restrict__ a1w2, const float* __restrict__ a1b2,
    const float* __restrict__ g1_tab, const int* __restrict__ a2_tab,
    float* __restrict__ out) {
  __shared__ __align__(16) float ring2[20][128];    // doubled ring (osum producer only)
  __shared__ __align__(16) float slotrec[10][512];  // [slot][j*4 + {r,z,n,h}]
  __shared__ __align__(16) float ghi4[512];         // [j*4 + {gi_r+bhh_r, gi_z+bhh_z, gi_n, bhh_n}]
  __shared__ __align__(16) float hbuf[128];         // h_{t-1} (matvec operand)
  __shared__ __align__(16) float obs[128];          // mean of ring
  __shared__ __align__(16) float osum[128];         // sum of 9 oldest ring entries (waves 2/3)
  __shared__ __align__(16) float z1buf[64];
  __shared__ __align__(16) float lastbuf[128];
  __shared__ __align__(16) float w2buf[10][68];     // padded (bank conflicts)
  __shared__ float b1s[64], b2s[10];
  __shared__ float g1buf[10];
  __shared__ float2 pl2[16];
  __shared__ int a2s_lds;
  __shared__ int redi[8];
  __shared__ int last_s;

  const int tid = threadIdx.x;
  const int wave = tid >> 6, lane = tid & 63;
  const int b = blockIdx.x;

  // ---- register-resident W_hh for waves 0-5: rows 4q+i, k-quad qk ----
  float4 wr[4][8];
  const int q = tid >> 2, qk = tid & 3;
  if (tid < 384) {
    #pragma unroll
    for (int i = 0; i < 4; i++) {
      const float* basep = w_hh + (size_t)(4 * q + i) * 128 + 4 * qk;
      #pragma unroll
      for (int c = 0; c < 8; c++) wr[i][c] = *(const float4*)(basep + 16 * c);
    }
  }
  // ---- register-resident a1w1 for waves 6/7 ----
  float4 w1reg[16];
  if (wave >= 6) {
    int m = ((wave - 6) << 5) + (lane >> 1);
    int kc = lane & 1;
    const float4* wp = (const float4*)(a1w1 + (size_t)m * 128 + 64 * kc);
    #pragma unroll
    for (int c = 0; c < 16; c++) w1reg[c] = wp[c];
  }
  // ---- wave 6: strided b_hh + gi regs (lane owns j=lane and j=64+lane) ----
  float bhh6[6] = {0.f, 0.f, 0.f, 0.f, 0.f, 0.f};
  float gc[6] = {0.f, 0.f, 0.f, 0.f, 0.f, 0.f};   // current step's gi
  if (wave == 6) {
    bhh6[0] = b_hh[lane];       bhh6[1] = b_hh[128 + lane]; bhh6[2] = b_hh[256 + lane];
    bhh6[3] = b_hh[64 + lane];  bhh6[4] = b_hh[192 + lane]; bhh6[5] = b_hh[320 + lane];
    const float* p1 = gi_glob + ((size_t)b * 512 + 1) * 384;
    gc[0] = p1[lane];      gc[1] = p1[128 + lane]; gc[2] = p1[256 + lane];
    gc[3] = p1[64 + lane]; gc[4] = p1[192 + lane]; gc[5] = p1[320 + lane];
  }
  float g1r = 0.f; int a2r = 0;
  if (wave == 7 && lane < 10) g1r = g1_tab[(size_t)b * 10 + lane];
  if (wave == 7 && lane == 12) a2r = a2_tab[b];

  // ---- LDS init ----
  for (int idx = tid; idx < 2560; idx += 512) ((float*)ring2)[idx] = 0.f;
  for (int idx = tid; idx < 5120; idx += 512) ((float*)slotrec)[idx] = 0.f;
  for (int idx = tid; idx < 640; idx += 512) w2buf[idx >> 6][idx & 63] = a1w2[idx];
  if (tid < 64) b1s[tid] = a1b1[tid];
  if (tid < 10) b2s[tid] = a1b2[tid];
  int mv = mask[(size_t)b * T_ + tid];
  #pragma unroll
  for (int off = 1; off < 64; off <<= 1) mv += __shfl_xor(mv, off);
  if (lane == 0) redi[wave] = mv;
  __syncthreads();
  if (tid == 0) {
    int s = 0;
    #pragma unroll
    for (int w = 0; w < 8; w++) s += redi[w];
    last_s = s - 1;
  }
  __syncthreads();
  const int last = last_s;

  // ---- t = 0: h0 = gru(x0, 0); obs for t=1 ----
  if (tid < 128) {
    int j = tid;
    const float* g0 = gi_glob + (size_t)b * 512 * 384;
    float r  = fsigmoid(g0[j] + b_hh[j]);
    float zz = fsigmoid(g0[128 + j] + b_hh[128 + j]);
    float n  = ftanh_(g0[256 + j] + r * b_hh[256 + j]);
    float hnew = (1.0f - zz) * n;
    hbuf[j] = hnew; ring2[0][j] = hnew; ring2[10][j] = hnew;
    slotrec[0][(j << 2) + 3] = hnew;
    obs[j] = hnew / 10.0f;
    __builtin_nontemporal_store(hnew, &out[BH_ + ((size_t)b * 512) * 128 + j]);
    if (0 == last) lastbuf[j] = hnew;
  }
  __syncthreads();

  // ---- t = 1..511 ----
  #pragma unroll 1
  for (int t = 1; t < T_; t++) {
    const int sn = (t + 9) % 10;   // slot of h_{t-1}
    if (tid < 384) {
      // ---- yc rows 4q..4q+3 of W_hh · h_{t-1} -> slotrec[sn] ----
      const float4* hb4 = (const float4*)hbuf;
      float4 a0 = make_float4(0.f, 0.f, 0.f, 0.f), a1v = a0, a2v = a0, a3v = a0;
      #pragma unroll
      for (int c = 0; c < 8; c++) {
        float4 h4 = hb4[4 * c + qk];
        a0.x += wr[0][c].x * h4.x; a0.y += wr[0][c].y * h4.y; a0.z += wr[0][c].z * h4.z; a0.w += wr[0][c].w * h4.w;
        a1v.x += wr[1][c].x * h4.x; a1v.y += wr[1][c].y * h4.y; a1v.z += wr[1][c].z * h4.z; a1v.w += wr[1][c].w * h4.w;
        a2v.x += wr[2][c].x * h4.x; a2v.y += wr[2][c].y * h4.y; a2v.z += wr[2][c].z * h4.z; a2v.w += wr[2][c].w * h4.w;
        a3v.x += wr[3][c].x * h4.x; a3v.y += wr[3][c].y * h4.y; a3v.z += wr[3][c].z * h4.z; a3v.w += wr[3][c].w * h4.w;
      }
      float s0  = (a0.x + a0.y) + (a0.z + a0.w);
      float s1v = (a1v.x + a1v.y) + (a1v.z + a1v.w);
      float s2v = (a2v.x + a2v.y) + (a2v.z + a2v.w);
      float s3v = (a3v.x + a3v.y) + (a3v.z + a3v.w);
      s0  = dpp_add_xor2(dpp_add_xor1(s0));
      s1v = dpp_add_xor2(dpp_add_xor1(s1v));
      s2v = dpp_add_xor2(dpp_add_xor1(s2v));
      s3v = dpp_add_xor2(dpp_add_xor1(s3v));
      float my = (qk == 0) ? s0 : (qk == 1) ? s1v : (qk == 2) ? s2v : s3v;
      // row = tid -> j = tid&127, gate = tid>>7
      slotrec[sn][((tid & 127) << 2) + (tid >> 7)] = my;
      // ---- waves 2/3: 9-entry ring sum for this step's obs update ----
      if (tid >= 128 && tid < 256) {
        int j = tid - 128;
        int bs = (t + 1) % 10;
        float s = 0.f;
        #pragma unroll
        for (int a = 0; a < 9; a++) s += ring2[bs + a][j];
        osum[j] = s;
      }
    } else if (wave == 6) {
      __builtin_amdgcn_s_setprio(1);
      // stage ghi4 records for j=lane and j=64+lane
      float4 e0, e1;
      e0.x = gc[0] + bhh6[0]; e0.y = gc[1] + bhh6[1]; e0.z = gc[2]; e0.w = bhh6[2];
      e1.x = gc[3] + bhh6[3]; e1.y = gc[4] + bhh6[4]; e1.z = gc[5]; e1.w = bhh6[5];
      ((float4*)ghi4)[lane] = e0;
      ((float4*)ghi4)[64 + lane] = e1;
      float gn0 = 0.f, gn1 = 0.f, gn2 = 0.f, gn3 = 0.f, gn4 = 0.f, gn5 = 0.f;
      if (t < 511) {
        const float* bp = gi_glob + ((size_t)b * 512 + t + 1) * 384;
        gn0 = bp[lane];      gn1 = bp[128 + lane]; gn2 = bp[256 + lane];
        gn3 = bp[64 + lane]; gn4 = bp[192 + lane]; gn5 = bp[320 + lane];
      }
      {
        int m = lane >> 1, kc = lane & 1;
        float ax = 0.f, ay = 0.f, az = 0.f, aw = 0.f;
        #pragma unroll
        for (int c = 0; c < 16; c++) {
          float4 o4 = ((const float4*)obs)[16 * kc + c];
          ax += w1reg[c].x * o4.x; ay += w1reg[c].y * o4.y;
          az += w1reg[c].z * o4.z; aw += w1reg[c].w * o4.w;
        }
        float d = (ax + ay) + (az + aw);
        d = dpp_add_xor1(d);
        if (kc == 0) z1buf[m] = ftanh_(d + b1s[m]);
      }
      if (lane < 40) {
        int a = lane >> 2, k2 = lane & 3;
        int m0 = 8 * k2;
        float4 z4a = ((const float4*)(z1buf + m0))[0], z4b = ((const float4*)(z1buf + m0))[1];
        float4 wa = ((const float4*)(&w2buf[a][m0]))[0], wb = ((const float4*)(&w2buf[a][m0]))[1];
        float p = z4a.x * wa.x + z4a.y * wa.y + z4a.z * wa.z + z4a.w * wa.w
                + z4b.x * wb.x + z4b.y * wb.y + z4b.z * wb.z + z4b.w * wb.w;
        p = dpp_add_xor2(dpp_add_xor1(p));
        if (k2 == 0) pl2[a].x = p + b2s[a];
      }
      gc[0] = gn0; gc[1] = gn1; gc[2] = gn2; gc[3] = gn3; gc[4] = gn4; gc[5] = gn5;
      __builtin_amdgcn_s_setprio(0);
    } else { // wave 7
      __builtin_amdgcn_s_setprio(1);
      if (lane < 10) g1buf[lane] = g1r;
      if (lane == 12) a2s_lds = a2r;
      if (t < 511) {
        if (lane < 10) g1r = g1_tab[((size_t)t * 256 + b) * 10 + lane];
        if (lane == 12) a2r = a2_tab[(size_t)t * 256 + b];
      }
      {
        int m = 32 + (lane >> 1), kc = lane & 1;
        float ax = 0.f, ay = 0.f, az = 0.f, aw = 0.f;
        #pragma unroll
        for (int c = 0; c < 16; c++) {
          float4 o4 = ((const float4*)obs)[16 * kc + c];
          ax += w1reg[c].x * o4.x; ay += w1reg[c].y * o4.y;
          az += w1reg[c].z * o4.z; aw += w1reg[c].w * o4.w;
        }
        float d = (ax + ay) + (az + aw);
        d = dpp_add_xor1(d);
        if (kc == 0) z1buf[m] = ftanh_(d + b1s[m]);
      }
      if (lane < 40) {
        int a = lane >> 2, k2 = lane & 3;
        int m0 = 32 + 8 * k2;
        float4 z4a = ((const float4*)(z1buf + m0))[0], z4b = ((const float4*)(z1buf + m0))[1];
        float4 wa = ((const float4*)(&w2buf[a][m0]))[0], wb = ((const float4*)(&w2buf[a][m0]))[1];
        float p = z4a.x * wa.x + z4a.y * wa.y + z4a.z * wa.z + z4a.w * wa.w
                + z4b.x * wb.x + z4b.y * wb.y + z4b.z * wb.z + z4b.w * wb.w;
        p = dpp_add_xor2(dpp_add_xor1(p));
        if (k2 == 0) pl2[a].y = p + g1buf[a];
      }
      __builtin_amdgcn_s_setprio(0);
    }
    bar_lds();   // slotrec/ghi4/pl2/a2s/osum ready

    if (tid < 128) {
      float best = 0.f; int bi = 0;
      #pragma unroll
      for (int a = 0; a < 10; a++) {
        float2 pv = pl2[a];
        float v = pv.x + pv.y;
        if (a == 0 || v > best) { best = v; bi = a; }
      }
      const int s1 = (t + bi) % 10;
      const int s2 = (t + a2s_lds) % 10;
      int j = tid;
      float4 y1 = *(const float4*)(&slotrec[s1][j << 2]);
      float4 y2 = *(const float4*)(&slotrec[s2][j << 2]);
      float4 yn = *(const float4*)(&slotrec[sn][j << 2]);
      float4 gv = ((const float4*)ghi4)[j];
      float gh1 = 0.5f * (0.5f * (y1.x + y2.x)) + 0.5f * yn.x;
      float gh2 = 0.5f * (0.5f * (y1.y + y2.y)) + 0.5f * yn.y;
      float gh3 = gv.w + 0.5f * (0.5f * (y1.z + y2.z)) + 0.5f * yn.z;
      float r  = fsigmoid(gv.x + gh1);
      float zz = fsigmoid(gv.y + gh2);
      float n  = ftanh_(gv.z + r * gh3);
      float hw = 0.5f * ((y1.w + y2.w) * 0.5f) + 0.5f * yn.w;
      float hnew = (1.0f - zz) * n + zz * hw;
      hbuf[j] = hnew;
      ring2[t % 10][j] = hnew;
      ring2[t % 10 + 10][j] = hnew;
      slotrec[t % 10][(j << 2) + 3] = hnew;
      __builtin_nontemporal_store(hnew, &out[BH_ + ((size_t)b * 512 + t) * 128 + j]);
      if (t == last) lastbuf[j] = hnew;
      obs[j] = (osum[j] + hnew) / 10.0f;   // osum precomputed by waves 2/3
    }
    bar_lds();   // hbuf/ring2/slotrec/obs ready for next step
  }
  if (tid < 128) __builtin_nontemporal_store(lastbuf[tid], &out[(size_t)b * H_ + tid]);
}

extern "C" void kernel_launch(void* const* d_in, const int* in_sizes, int n_in,
                              void* d_out, int out_size, void* d_ws, size_t ws_size,
                              hipStream_t stream) {
  (void)in_sizes; (void)n_in; (void)out_size; (void)ws_size;
  const float* x     = (const float*)d_in[0];
  const int*   mask  = (const int*)d_in[1];
  const float* w_ih  = (const float*)d_in[2];
  const float* w_hh  = (const float*)d_in[3];
  const float* b_ih  = (const float*)d_in[4];
  const float* b_hh  = (const float*)d_in[5];
  const float* a1w1  = (const float*)d_in[6];
  const float* a1b1  = (const float*)d_in[7];
  const float* a1w2  = (const float*)d_in[8];
  const float* a1b2  = (const float*)d_in[9];
  const float* a2w1  = (const float*)d_in[10];
  const float* a2b1  = (const float*)d_in[11];
  const float* a2w2  = (const float*)d_in[12];
  const float* a2b2  = (const float*)d_in[13];
  float* out = (float*)d_out;

  // workspace: gi (201.3 MB) | g1 (5.2 MB) | keys | a2_tab | z table (33.5 MB)
  float*    gi       = (float*)d_ws;
  float*    g1       = gi + (size_t)131072 * 384;
  unsigned* keys_tab = (unsigned*)(g1 + NG);
  int*      a2_tab   = (int*)(keys_tab + 2048);
  float*    zt       = (float*)(a2_tab + 130816);

  p0_keys<<<4, 256, 0, stream>>>(keys_tab);
  gemm_tiled<<<3584, 256, 0, stream>>>(x, w_ih, b_ih, a2w1, a2b1, gi, zt);
  sampler<<<511, 256, 0, stream>>>(zt, a2w2, a2b2, keys_tab, g1, a2_tab);
  seq_kernel<<<256, 512, 0, stream>>>(gi, mask, w_hh, b_hh,
                                      a1w1, a1b1, a1w2, a1b2, g1, a2_tab, out);
}